// Round 4
// baseline (91.276 us; speedup 1.0000x reference)
//
#include <hip/hip_runtime.h>
#include <stdint.h>

typedef _Float16 f16x8 __attribute__((ext_vector_type(8)));
typedef float f32x4 __attribute__((ext_vector_type(4)));

#define MFMA16(a, b, c) __builtin_amdgcn_mfma_f32_16x16x32_f16(a, b, c, 0, 0, 0)

static __device__ __forceinline__ uint32_t pkh(float a, float b) {
    union { _Float16 h[2]; uint32_t u; } v;
    v.h[0] = (_Float16)a; v.h[1] = (_Float16)b;
    return v.u;
}

__launch_bounds__(512, 1)
__global__ void cnf_main(const float* __restrict__ y,
                         const float* __restrict__ W1, const float* __restrict__ b1,
                         const float* __restrict__ W2, const float* __restrict__ b2,
                         const float* __restrict__ W3, const float* __restrict__ b3,
                         float* __restrict__ out) {
    // subtiled [kb=row>>3][col][row&7] f16: B-frag read = one ds_read_b128
    __shared__ _Float16 H1[16 * 128];
    __shared__ _Float16 H2[16 * 128];
    __shared__ _Float16 S2[16 * 128];
    __shared__ float PS[8 * 16];

    const int tid   = threadIdx.x;
    const int w     = tid >> 6;      // 8 waves, wave owns hidden rows [w*16, w*16+16)
    const int l     = tid & 63;
    const int col   = l & 15;        // sample column / A-frag tile row
    const int g4    = l >> 4;
    const int sbase = blockIdx.x * 16;
    const int arow  = w * 16 + col;          // A-frag hidden row
    const int crow  = w * 16 + g4 * 4;       // C-layout hidden row base

    // ---- stationary fragments ----
    f16x8 W2f[4], Gf[4], Mf[4];
#pragma unroll
    for (int ks = 0; ks < 4; ++ks) {
        const float4* pw = (const float4*)&W2[arow * 128 + ks * 32 + g4 * 8];
        float4 a0 = pw[0], a1 = pw[1];
        f16x8 t = {(_Float16)a0.x, (_Float16)a0.y, (_Float16)a0.z, (_Float16)a0.w,
                   (_Float16)a1.x, (_Float16)a1.y, (_Float16)a1.z, (_Float16)a1.w};
        W2f[ks] = t;
    }
    // M = W1y @ W3 ; Mf = f16(M), Gf = f16(M .* W2^T). Per-ks to keep pressure low.
    {
        float w1row[16];
#pragma unroll
        for (int m = 0; m < 16; ++m) w1row[m] = W1[arow * 17 + m];
#pragma unroll
        for (int ks = 0; ks < 4; ++ks) {
            float macc[8];
#pragma unroll
            for (int j = 0; j < 8; ++j) macc[j] = 0.f;
#pragma unroll
            for (int m = 0; m < 16; ++m) {
                const float4* pr = (const float4*)&W3[m * 128 + ks * 32 + g4 * 8];
                float4 r0 = pr[0], r1 = pr[1];
                float wv = w1row[m];
                macc[0] += wv * r0.x; macc[1] += wv * r0.y;
                macc[2] += wv * r0.z; macc[3] += wv * r0.w;
                macc[4] += wv * r1.x; macc[5] += wv * r1.y;
                macc[6] += wv * r1.z; macc[7] += wv * r1.w;
            }
            f16x8 mh, gh;
#pragma unroll
            for (int j = 0; j < 8; ++j) {
                mh[j] = (_Float16)macc[j];
                gh[j] = (_Float16)(macc[j] * W2[(ks * 32 + g4 * 8 + j) * 128 + arow]);
            }
            Mf[ks] = mh;
            Gf[ks] = gh;
        }
    }

    // biases / projections
    float b1r[4], b2r[4], w1t[4], ub3[4];
#pragma unroll
    for (int r = 0; r < 4; ++r) {
        b1r[r] = b1[crow + r];
        b2r[r] = b2[crow + r];
        w1t[r] = W1[(crow + r) * 17 + 16];
        float acc = 0.f;
#pragma unroll
        for (int m = 0; m < 16; ++m) acc += W1[(crow + r) * 17 + m] * b3[m];
        ub3[r] = acc;   // (W1y @ b3)[crow+r]
    }

    // ---- init: uc = W1y @ y0 via one MFMA ----
    f32x4 uc, uh, uf = {0.f, 0.f, 0.f, 0.f}, hacc = {0.f, 0.f, 0.f, 0.f};
    {
        union { uint32_t u[4]; f16x8 f; } yu, wu;
#pragma unroll
        for (int q = 0; q < 4; ++q) { yu.u[q] = 0u; wu.u[q] = 0u; }
        if (g4 < 2) {
            const float4* py = (const float4*)&y[(sbase + col) * 16 + g4 * 8];
            float4 y0 = py[0], y1 = py[1];
            yu.u[0] = pkh(y0.x, y0.y); yu.u[1] = pkh(y0.z, y0.w);
            yu.u[2] = pkh(y1.x, y1.y); yu.u[3] = pkh(y1.z, y1.w);
            wu.u[0] = pkh(W1[arow * 17 + g4 * 8 + 0], W1[arow * 17 + g4 * 8 + 1]);
            wu.u[1] = pkh(W1[arow * 17 + g4 * 8 + 2], W1[arow * 17 + g4 * 8 + 3]);
            wu.u[2] = pkh(W1[arow * 17 + g4 * 8 + 4], W1[arow * 17 + g4 * 8 + 5]);
            wu.u[3] = pkh(W1[arow * 17 + g4 * 8 + 6], W1[arow * 17 + g4 * 8 + 7]);
        }
        f32x4 z0 = {0.f, 0.f, 0.f, 0.f};
        uc = MFMA16(wu.f, yu.f, z0);
    }
    uh = uc;

    float plsum = 0.f;
    const int hidx = ((crow >> 3) * 16 + col) * 8 + (crow & 7);

    for (int e = 0; e <= 10; ++e) {
        const float t  = 0.1f * (float)e;
        const float wt = (e == 0 || e == 10) ? 0.05f : 0.1f;

        // ---- layer 1 entirely in registers: z1 = uh' + t*w1t + b1 ----
        f32x4 z1;
        if (e == 0) {
#pragma unroll
            for (int r = 0; r < 4; ++r) z1[r] = uc[r] + b1r[r];
        } else {
#pragma unroll
            for (int r = 0; r < 4; ++r) {
                uh[r] = 2.f * uc[r] - uh[r] + 0.1f * uf[r];
                z1[r] = uh[r] + t * w1t[r] + b1r[r];
            }
        }
        float s1v[4];
        {
            float h1v[4];
#pragma unroll
            for (int r = 0; r < 4; ++r) {
                float zz = z1[r];
                float g  = 1.f / (1.f + __expf(-zz));
                float hh = zz * g;
                h1v[r] = hh;
                s1v[r] = g + hh * (1.f - g);
            }
            uint32_t* p = (uint32_t*)&H1[hidx];
            p[0] = pkh(h1v[0], h1v[1]);
            p[1] = pkh(h1v[2], h1v[3]);
        }
        __syncthreads();   // A: H1 ready

        // ---- layer 2: z2 = W2 @ H1 + b2 ----
        f16x8 Bf[4];
#pragma unroll
        for (int ks = 0; ks < 4; ++ks)
            Bf[ks] = *(const f16x8*)&H1[(g4 + ks * 4) * 128 + col * 8];
        f32x4 ca = {b2r[0], b2r[1], b2r[2], b2r[3]};
        f32x4 cb = {0.f, 0.f, 0.f, 0.f};
        ca = MFMA16(W2f[0], Bf[0], ca); cb = MFMA16(W2f[1], Bf[1], cb);
        ca = MFMA16(W2f[2], Bf[2], ca); cb = MFMA16(W2f[3], Bf[3], cb);
        {
            float h2v[4], s2v[4];
#pragma unroll
            for (int r = 0; r < 4; ++r) {
                float zz = ca[r] + cb[r];
                float g  = 1.f / (1.f + __expf(-zz));
                float hh = zz * g;
                h2v[r] = hh;
                s2v[r] = g + hh * (1.f - g);
                hacc[r] += wt * hh;     // y-output accumulator (linear in h2)
            }
            if (e < 10) {
                uint32_t* p = (uint32_t*)&H2[hidx];
                p[0] = pkh(h2v[0], h2v[1]);
                p[1] = pkh(h2v[2], h2v[3]);
            }
            uint32_t* p = (uint32_t*)&S2[hidx];
            p[0] = pkh(s2v[0], s2v[1]);
            p[1] = pkh(s2v[2], s2v[3]);
        }
        __syncthreads();   // B: H2, S2 ready

        // ---- trace partial ----
        f16x8 Sf[4];
#pragma unroll
        for (int ks = 0; ks < 4; ++ks)
            Sf[ks] = *(const f16x8*)&S2[(g4 + ks * 4) * 128 + col * 8];
        f32x4 c0 = {0.f, 0.f, 0.f, 0.f}, c1 = {0.f, 0.f, 0.f, 0.f};
        c0 = MFMA16(Gf[0], Sf[0], c0); c1 = MFMA16(Gf[1], Sf[1], c1);
        c0 = MFMA16(Gf[2], Sf[2], c0); c1 = MFMA16(Gf[3], Sf[3], c1);
        float p = 0.f;
#pragma unroll
        for (int r = 0; r < 4; ++r) p += s1v[r] * (c0[r] + c1[r]);
        p += __shfl_xor(p, 16);
        p += __shfl_xor(p, 32);
        plsum += wt * p;

        // ---- uf_next = M @ H2 + W1y@b3 ; state update (skip at e=10) ----
        if (e < 10) {
            f16x8 Hf[4];
#pragma unroll
            for (int ks = 0; ks < 4; ++ks)
                Hf[ks] = *(const f16x8*)&H2[(g4 + ks * 4) * 128 + col * 8];
            f32x4 u0 = {ub3[0], ub3[1], ub3[2], ub3[3]};
            f32x4 u1 = {0.f, 0.f, 0.f, 0.f};
            u0 = MFMA16(Mf[0], Hf[0], u0); u1 = MFMA16(Mf[1], Hf[1], u1);
            u0 = MFMA16(Mf[2], Hf[2], u0); u1 = MFMA16(Mf[3], Hf[3], u1);
            if (e == 0) {
#pragma unroll
                for (int r = 0; r < 4; ++r) uf[r] = u0[r] + u1[r];
            } else {
#pragma unroll
                for (int r = 0; r < 4; ++r) {
                    float un = u0[r] + u1[r];
                    uc[r] += 0.05f * (uf[r] + un);
                    uf[r] = un;
                }
            }
        }
    }

    // ---- epilogue: y_out = y0 + W3 @ hacc + b3 ; l_out = sum of wave partials ----
    {
        uint32_t* p = (uint32_t*)&H2[hidx];     // safe: barrier B since last H2 read
        p[0] = pkh(hacc[0], hacc[1]);
        p[1] = pkh(hacc[2], hacc[3]);
    }
    if (l < 16) PS[w * 16 + l] = plsum;
    __syncthreads();
    if (w == 0) {
        f16x8 Hf[4], W3w[4];
#pragma unroll
        for (int ks = 0; ks < 4; ++ks) {
            Hf[ks] = *(const f16x8*)&H2[(g4 + ks * 4) * 128 + col * 8];
            const float4* pw = (const float4*)&W3[col * 128 + ks * 32 + g4 * 8];
            float4 a0 = pw[0], a1 = pw[1];
            f16x8 t = {(_Float16)a0.x, (_Float16)a0.y, (_Float16)a0.z, (_Float16)a0.w,
                       (_Float16)a1.x, (_Float16)a1.y, (_Float16)a1.z, (_Float16)a1.w};
            W3w[ks] = t;
        }
        f32x4 f0 = {b3[g4 * 4 + 0], b3[g4 * 4 + 1], b3[g4 * 4 + 2], b3[g4 * 4 + 3]};
        f32x4 f1 = {0.f, 0.f, 0.f, 0.f};
        f0 = MFMA16(W3w[0], Hf[0], f0); f1 = MFMA16(W3w[1], Hf[1], f1);
        f0 = MFMA16(W3w[2], Hf[2], f0); f1 = MFMA16(W3w[3], Hf[3], f1);
#pragma unroll
        for (int r = 0; r < 4; ++r)
            out[(sbase + col) * 16 + g4 * 4 + r] =
                y[(sbase + col) * 16 + g4 * 4 + r] + f0[r] + f1[r];
        if (l < 16) {
            float s = 0.f;
#pragma unroll
            for (int ww = 0; ww < 8; ++ww) s += PS[ww * 16 + l];
            out[4096 * 16 + sbase + l] = s;
        }
    }
}

extern "C" void kernel_launch(void* const* d_in, const int* in_sizes, int n_in,
                              void* d_out, int out_size, void* d_ws, size_t ws_size,
                              hipStream_t stream) {
    const float* y  = (const float*)d_in[0];
    const float* W1 = (const float*)d_in[1];
    const float* b1 = (const float*)d_in[2];
    const float* W2 = (const float*)d_in[3];
    const float* b2 = (const float*)d_in[4];
    const float* W3 = (const float*)d_in[5];
    const float* b3 = (const float*)d_in[6];
    float* out = (float*)d_out;

    cnf_main<<<256, 512, 0, stream>>>(y, W1, b1, W2, b2, W3, b3, out);
}

// Round 5
// 81.300 us; speedup vs baseline: 1.1227x; 1.1227x over previous
//
#include <hip/hip_runtime.h>
#include <stdint.h>

typedef _Float16 f16x8 __attribute__((ext_vector_type(8)));
typedef float f32x4 __attribute__((ext_vector_type(4)));

#define MFMA16(a, b, c) __builtin_amdgcn_mfma_f32_16x16x32_f16(a, b, c, 0, 0, 0)

static __device__ __forceinline__ uint32_t pkh(float a, float b) {
    union { _Float16 h[2]; uint32_t u; } v;
    v.h[0] = (_Float16)a; v.h[1] = (_Float16)b;
    return v.u;
}

__launch_bounds__(256, 1)
__global__ void cnf_main(const float* __restrict__ y,
                         const float* __restrict__ W1, const float* __restrict__ b1,
                         const float* __restrict__ W2, const float* __restrict__ b2,
                         const float* __restrict__ W3, const float* __restrict__ b3,
                         float* __restrict__ out) {
    // subtiled [kb=row>>3][col][row&7] f16: B-frag read = one ds_read_b128
    __shared__ _Float16 H1[16 * 128];
    __shared__ _Float16 H2[16 * 128];
    __shared__ _Float16 S2[16 * 128];
    __shared__ float PS[4 * 16];

    const int tid   = threadIdx.x;
    const int w     = tid >> 6;      // 4 waves, wave owns hidden rows [w*32, w*32+32)
    const int l     = tid & 63;
    const int col   = l & 15;        // sample column / A-frag tile row
    const int g4    = l >> 4;
    const int sbase = blockIdx.x * 16;

    // ---- stationary fragments (2 m-tiles of 16 rows per wave) ----
    f16x8 W2f[2][4], Gf[2][4], Mf[2][4];
    float b1r[2][4], b2r[2][4], w1t[2][4], ub3[2][4];
#pragma unroll
    for (int m = 0; m < 2; ++m) {
        const int arow = w * 32 + m * 16 + col;     // A-frag hidden row
        const int crow = w * 32 + m * 16 + g4 * 4;  // C-layout hidden row base
#pragma unroll
        for (int ks = 0; ks < 4; ++ks) {
            const float4* pw = (const float4*)&W2[arow * 128 + ks * 32 + g4 * 8];
            float4 a0 = pw[0], a1 = pw[1];
            f16x8 t = {(_Float16)a0.x, (_Float16)a0.y, (_Float16)a0.z, (_Float16)a0.w,
                       (_Float16)a1.x, (_Float16)a1.y, (_Float16)a1.z, (_Float16)a1.w};
            W2f[m][ks] = t;
        }
        // M = W1y @ W3 ; Mf = f16(M), Gf = f16(M .* W2^T) — per-ks to cap pressure
        {
            float w1row[16];
#pragma unroll
            for (int mm = 0; mm < 16; ++mm) w1row[mm] = W1[arow * 17 + mm];
#pragma unroll
            for (int ks = 0; ks < 4; ++ks) {
                float macc[8];
#pragma unroll
                for (int j = 0; j < 8; ++j) macc[j] = 0.f;
#pragma unroll
                for (int mm = 0; mm < 16; ++mm) {
                    const float4* pr = (const float4*)&W3[mm * 128 + ks * 32 + g4 * 8];
                    float4 r0 = pr[0], r1 = pr[1];
                    float wv = w1row[mm];
                    macc[0] += wv * r0.x; macc[1] += wv * r0.y;
                    macc[2] += wv * r0.z; macc[3] += wv * r0.w;
                    macc[4] += wv * r1.x; macc[5] += wv * r1.y;
                    macc[6] += wv * r1.z; macc[7] += wv * r1.w;
                }
                f16x8 mh, gh;
#pragma unroll
                for (int j = 0; j < 8; ++j) {
                    mh[j] = (_Float16)macc[j];
                    gh[j] = (_Float16)(macc[j] * W2[(ks * 32 + g4 * 8 + j) * 128 + arow]);
                }
                Mf[m][ks] = mh;
                Gf[m][ks] = gh;
            }
        }
#pragma unroll
        for (int r = 0; r < 4; ++r) {
            b1r[m][r] = b1[crow + r];
            b2r[m][r] = b2[crow + r];
            w1t[m][r] = W1[(crow + r) * 17 + 16];
            float acc = 0.f;
#pragma unroll
            for (int mm = 0; mm < 16; ++mm) acc += W1[(crow + r) * 17 + mm] * b3[mm];
            ub3[m][r] = acc;   // (W1y @ b3)[crow+r]
        }
    }

    // ---- init: uc = W1y @ y0 (one MFMA per m-tile) ----
    f32x4 uc[2], uh[2], uf[2], hacc[2];
    {
        union { uint32_t u[4]; f16x8 f; } yu;
#pragma unroll
        for (int q = 0; q < 4; ++q) yu.u[q] = 0u;
        if (g4 < 2) {
            const float4* py = (const float4*)&y[(sbase + col) * 16 + g4 * 8];
            float4 y0 = py[0], y1 = py[1];
            yu.u[0] = pkh(y0.x, y0.y); yu.u[1] = pkh(y0.z, y0.w);
            yu.u[2] = pkh(y1.x, y1.y); yu.u[3] = pkh(y1.z, y1.w);
        }
#pragma unroll
        for (int m = 0; m < 2; ++m) {
            const int arow = w * 32 + m * 16 + col;
            union { uint32_t u[4]; f16x8 f; } wu;
#pragma unroll
            for (int q = 0; q < 4; ++q) wu.u[q] = 0u;
            if (g4 < 2) {
                wu.u[0] = pkh(W1[arow * 17 + g4 * 8 + 0], W1[arow * 17 + g4 * 8 + 1]);
                wu.u[1] = pkh(W1[arow * 17 + g4 * 8 + 2], W1[arow * 17 + g4 * 8 + 3]);
                wu.u[2] = pkh(W1[arow * 17 + g4 * 8 + 4], W1[arow * 17 + g4 * 8 + 5]);
                wu.u[3] = pkh(W1[arow * 17 + g4 * 8 + 6], W1[arow * 17 + g4 * 8 + 7]);
            }
            f32x4 z0 = {0.f, 0.f, 0.f, 0.f};
            uc[m] = MFMA16(wu.f, yu.f, z0);
            uh[m] = uc[m];
            uf[m] = z0;
            hacc[m] = z0;
        }
    }

    float plsum = 0.f;
    int hidx[2];
#pragma unroll
    for (int m = 0; m < 2; ++m) {
        const int crow = w * 32 + m * 16 + g4 * 4;
        hidx[m] = ((crow >> 3) * 16 + col) * 8 + (crow & 7);
    }

    for (int e = 0; e <= 10; ++e) {
        const float t  = 0.1f * (float)e;
        const float wt = (e == 0 || e == 10) ? 0.05f : 0.1f;

        // ---- layer 1 in registers: z1 = uh' + t*w1t + b1 ; h1 -> LDS ----
        float s1v[2][4];
#pragma unroll
        for (int m = 0; m < 2; ++m) {
            f32x4 z1;
            if (e == 0) {
#pragma unroll
                for (int r = 0; r < 4; ++r) z1[r] = uc[m][r] + b1r[m][r];
            } else {
#pragma unroll
                for (int r = 0; r < 4; ++r) {
                    uh[m][r] = 2.f * uc[m][r] - uh[m][r] + 0.1f * uf[m][r];
                    z1[r] = uh[m][r] + t * w1t[m][r] + b1r[m][r];
                }
            }
            float h1v[4];
#pragma unroll
            for (int r = 0; r < 4; ++r) {
                float zz = z1[r];
                float g  = 1.f / (1.f + __expf(-zz));
                float hh = zz * g;
                h1v[r] = hh;
                s1v[m][r] = g + hh * (1.f - g);
            }
            uint32_t* p = (uint32_t*)&H1[hidx[m]];
            p[0] = pkh(h1v[0], h1v[1]);
            p[1] = pkh(h1v[2], h1v[3]);
        }
        __syncthreads();   // A: H1 ready

        // ---- layer 2: z2 = W2 @ H1 + b2 ; h2, silu'2 -> LDS ----
        f16x8 Bf[4];
#pragma unroll
        for (int ks = 0; ks < 4; ++ks)
            Bf[ks] = *(const f16x8*)&H1[(g4 + ks * 4) * 128 + col * 8];
#pragma unroll
        for (int m = 0; m < 2; ++m) {
            f32x4 ca = {b2r[m][0], b2r[m][1], b2r[m][2], b2r[m][3]};
            f32x4 cb = {0.f, 0.f, 0.f, 0.f};
            ca = MFMA16(W2f[m][0], Bf[0], ca); cb = MFMA16(W2f[m][1], Bf[1], cb);
            ca = MFMA16(W2f[m][2], Bf[2], ca); cb = MFMA16(W2f[m][3], Bf[3], cb);
            float h2v[4], s2v[4];
#pragma unroll
            for (int r = 0; r < 4; ++r) {
                float zz = ca[r] + cb[r];
                float g  = 1.f / (1.f + __expf(-zz));
                float hh = zz * g;
                h2v[r] = hh;
                s2v[r] = g + hh * (1.f - g);
                hacc[m][r] += wt * hh;     // y-output accumulator (linear in h2)
            }
            if (e < 10) {
                uint32_t* p = (uint32_t*)&H2[hidx[m]];
                p[0] = pkh(h2v[0], h2v[1]);
                p[1] = pkh(h2v[2], h2v[3]);
            }
            uint32_t* p = (uint32_t*)&S2[hidx[m]];
            p[0] = pkh(s2v[0], s2v[1]);
            p[1] = pkh(s2v[2], s2v[3]);
        }
        __syncthreads();   // B: H2, S2 ready

        // ---- trace partial ----
        f16x8 Sf[4];
#pragma unroll
        for (int ks = 0; ks < 4; ++ks)
            Sf[ks] = *(const f16x8*)&S2[(g4 + ks * 4) * 128 + col * 8];
        float p = 0.f;
#pragma unroll
        for (int m = 0; m < 2; ++m) {
            f32x4 c0 = {0.f, 0.f, 0.f, 0.f}, c1 = {0.f, 0.f, 0.f, 0.f};
            c0 = MFMA16(Gf[m][0], Sf[0], c0); c1 = MFMA16(Gf[m][1], Sf[1], c1);
            c0 = MFMA16(Gf[m][2], Sf[2], c0); c1 = MFMA16(Gf[m][3], Sf[3], c1);
#pragma unroll
            for (int r = 0; r < 4; ++r) p += s1v[m][r] * (c0[r] + c1[r]);
        }
        p += __shfl_xor(p, 16);
        p += __shfl_xor(p, 32);
        plsum += wt * p;

        // ---- uf_next = M @ H2 + W1y@b3 ; state update (skip at e=10) ----
        if (e < 10) {
            f16x8 Hf[4];
#pragma unroll
            for (int ks = 0; ks < 4; ++ks)
                Hf[ks] = *(const f16x8*)&H2[(g4 + ks * 4) * 128 + col * 8];
#pragma unroll
            for (int m = 0; m < 2; ++m) {
                f32x4 u0 = {ub3[m][0], ub3[m][1], ub3[m][2], ub3[m][3]};
                f32x4 u1 = {0.f, 0.f, 0.f, 0.f};
                u0 = MFMA16(Mf[m][0], Hf[0], u0); u1 = MFMA16(Mf[m][1], Hf[1], u1);
                u0 = MFMA16(Mf[m][2], Hf[2], u0); u1 = MFMA16(Mf[m][3], Hf[3], u1);
                if (e == 0) {
#pragma unroll
                    for (int r = 0; r < 4; ++r) uf[m][r] = u0[r] + u1[r];
                } else {
#pragma unroll
                    for (int r = 0; r < 4; ++r) {
                        float un = u0[r] + u1[r];
                        uc[m][r] += 0.05f * (uf[m][r] + un);
                        uf[m][r] = un;
                    }
                }
            }
        }
    }

    // ---- epilogue: y_out = y0 + W3 @ hacc + b3 ; l_out = wave-partial sum ----
#pragma unroll
    for (int m = 0; m < 2; ++m) {
        uint32_t* p = (uint32_t*)&H2[hidx[m]];   // safe: barrier A of e=10 since last read
        p[0] = pkh(hacc[m][0], hacc[m][1]);
        p[1] = pkh(hacc[m][2], hacc[m][3]);
    }
    if (l < 16) PS[w * 16 + l] = plsum;
    __syncthreads();
    if (w == 0) {
        f16x8 Hf[4], W3w[4];
#pragma unroll
        for (int ks = 0; ks < 4; ++ks) {
            Hf[ks] = *(const f16x8*)&H2[(g4 + ks * 4) * 128 + col * 8];
            const float4* pw = (const float4*)&W3[col * 128 + ks * 32 + g4 * 8];
            float4 a0 = pw[0], a1 = pw[1];
            f16x8 t = {(_Float16)a0.x, (_Float16)a0.y, (_Float16)a0.z, (_Float16)a0.w,
                       (_Float16)a1.x, (_Float16)a1.y, (_Float16)a1.z, (_Float16)a1.w};
            W3w[ks] = t;
        }
        f32x4 f0 = {b3[g4 * 4 + 0], b3[g4 * 4 + 1], b3[g4 * 4 + 2], b3[g4 * 4 + 3]};
        f32x4 f1 = {0.f, 0.f, 0.f, 0.f};
        f0 = MFMA16(W3w[0], Hf[0], f0); f1 = MFMA16(W3w[1], Hf[1], f1);
        f0 = MFMA16(W3w[2], Hf[2], f0); f1 = MFMA16(W3w[3], Hf[3], f1);
#pragma unroll
        for (int r = 0; r < 4; ++r)
            out[(sbase + col) * 16 + g4 * 4 + r] =
                y[(sbase + col) * 16 + g4 * 4 + r] + f0[r] + f1[r];
        if (l < 16) {
            float s = 0.f;
#pragma unroll
            for (int ww = 0; ww < 4; ++ww) s += PS[ww * 16 + l];
            out[4096 * 16 + sbase + l] = s;
        }
    }
}

extern "C" void kernel_launch(void* const* d_in, const int* in_sizes, int n_in,
                              void* d_out, int out_size, void* d_ws, size_t ws_size,
                              hipStream_t stream) {
    const float* y  = (const float*)d_in[0];
    const float* W1 = (const float*)d_in[1];
    const float* b1 = (const float*)d_in[2];
    const float* W2 = (const float*)d_in[3];
    const float* b2 = (const float*)d_in[4];
    const float* W3 = (const float*)d_in[5];
    const float* b3 = (const float*)d_in[6];
    float* out = (float*)d_out;

    cnf_main<<<256, 256, 0, stream>>>(y, W1, b1, W2, b2, W3, b3, out);
}

// Round 6
// 49.627 us; speedup vs baseline: 1.8393x; 1.6382x over previous
//
#include <hip/hip_runtime.h>
#include <stdint.h>

typedef _Float16 f16x8 __attribute__((ext_vector_type(8)));
typedef float f32x4 __attribute__((ext_vector_type(4)));

#define MFMA16(a, b, c) __builtin_amdgcn_mfma_f32_16x16x32_f16(a, b, c, 0, 0, 0)

static __device__ __forceinline__ uint32_t pkh(float a, float b) {
    union { _Float16 h[2]; uint32_t u; } v;
    v.h[0] = (_Float16)a; v.h[1] = (_Float16)b;
    return v.u;
}

// A-fragment LDS slot: tile T (rows T*16..T*16+15), k-block ks, lane l -> 8 f16
#define AFOFF(T, ks, l) (((((T) * 4 + (ks)) * 64) + (l)) * 8)

__launch_bounds__(256, 1)
__global__ void cnf_main(const float* __restrict__ y,
                         const float* __restrict__ W1, const float* __restrict__ b1,
                         const float* __restrict__ W2, const float* __restrict__ b2,
                         const float* __restrict__ W3, const float* __restrict__ b3,
                         float* __restrict__ out) {
    // G and M stationary A-fragments live in LDS (fragment-linear, conflict-free
    // b128 reads, zero cross-wave sharing) — LDS as spill-proof register file.
    __shared__ _Float16 AG[8 * 4 * 64 * 8];   // 32 KB
    __shared__ _Float16 AM[8 * 4 * 64 * 8];   // 32 KB
    // subtiled [kb=row>>3][col][row&7] f16: B-frag read = one ds_read_b128
    __shared__ _Float16 H1[16 * 128];
    __shared__ _Float16 H2[16 * 128];
    __shared__ _Float16 S2[16 * 128];
    __shared__ float PS[4 * 16];

    const int tid   = threadIdx.x;
    const int w     = tid >> 6;      // 4 waves, wave owns hidden rows [w*32, w*32+32)
    const int l     = tid & 63;
    const int col   = l & 15;        // sample column / A-frag tile row
    const int g4    = l >> 4;
    const int sbase = blockIdx.x * 16;

    // ---- W2 A-fragments in registers (proven spill-free at this count) ----
    f16x8 W2f[2][4];
#pragma unroll
    for (int m = 0; m < 2; ++m) {
        const int arow = w * 32 + m * 16 + col;
#pragma unroll
        for (int ks = 0; ks < 4; ++ks) {
            const float4* pw = (const float4*)&W2[arow * 128 + ks * 32 + g4 * 8];
            float4 a0 = pw[0], a1 = pw[1];
            f16x8 t = {(_Float16)a0.x, (_Float16)a0.y, (_Float16)a0.z, (_Float16)a0.w,
                       (_Float16)a1.x, (_Float16)a1.y, (_Float16)a1.z, (_Float16)a1.w};
            W2f[m][ks] = t;
        }
    }

    // ---- prologue: M = W1y@W3, G = M .* W2^T  -> LDS fragments ----
#pragma unroll
    for (int m = 0; m < 2; ++m) {
        const int T = w * 2 + m;
        const int arow = T * 16 + col;
        float w1row[16];
#pragma unroll
        for (int mm = 0; mm < 16; ++mm) w1row[mm] = W1[arow * 17 + mm];
#pragma unroll
        for (int ks = 0; ks < 4; ++ks) {
            float macc[8];
#pragma unroll
            for (int j = 0; j < 8; ++j) macc[j] = 0.f;
#pragma unroll
            for (int mm = 0; mm < 16; ++mm) {
                const float4* pr = (const float4*)&W3[mm * 128 + ks * 32 + g4 * 8];
                float4 r0 = pr[0], r1 = pr[1];
                float wv = w1row[mm];
                macc[0] += wv * r0.x; macc[1] += wv * r0.y;
                macc[2] += wv * r0.z; macc[3] += wv * r0.w;
                macc[4] += wv * r1.x; macc[5] += wv * r1.y;
                macc[6] += wv * r1.z; macc[7] += wv * r1.w;
            }
            f16x8 mh, gh;
#pragma unroll
            for (int j = 0; j < 8; ++j) {
                mh[j] = (_Float16)macc[j];
                gh[j] = (_Float16)(macc[j] * W2[(ks * 32 + g4 * 8 + j) * 128 + arow]);
            }
            *(f16x8*)&AM[AFOFF(T, ks, l)] = mh;
            *(f16x8*)&AG[AFOFF(T, ks, l)] = gh;
        }
    }

    // ---- biases / projections ----
    float b1r[2][4], b2r[2][4], w1t[2][4], ub3[2][4];
#pragma unroll
    for (int m = 0; m < 2; ++m) {
        const int crow = w * 32 + m * 16 + g4 * 4;
#pragma unroll
        for (int r = 0; r < 4; ++r) {
            b1r[m][r] = b1[crow + r];
            b2r[m][r] = b2[crow + r];
            w1t[m][r] = W1[(crow + r) * 17 + 16];
            float acc = 0.f;
#pragma unroll
            for (int mm = 0; mm < 16; ++mm) acc += W1[(crow + r) * 17 + mm] * b3[mm];
            ub3[m][r] = acc;   // (W1y @ b3)[crow+r]
        }
    }

    // ---- init: uc = W1y @ y0 (one MFMA per m-tile); uh=uc, uf=0 ----
    f32x4 uc[2], uh[2], uf[2], hacc[2];
    {
        union { uint32_t u[4]; f16x8 f; } yu;
#pragma unroll
        for (int q = 0; q < 4; ++q) yu.u[q] = 0u;
        if (g4 < 2) {
            const float4* py = (const float4*)&y[(sbase + col) * 16 + g4 * 8];
            float4 y0 = py[0], y1 = py[1];
            yu.u[0] = pkh(y0.x, y0.y); yu.u[1] = pkh(y0.z, y0.w);
            yu.u[2] = pkh(y1.x, y1.y); yu.u[3] = pkh(y1.z, y1.w);
        }
#pragma unroll
        for (int m = 0; m < 2; ++m) {
            const int arow = w * 32 + m * 16 + col;
            union { uint32_t u[4]; f16x8 f; } wu;
#pragma unroll
            for (int q = 0; q < 4; ++q) wu.u[q] = 0u;
            if (g4 < 2) {
                wu.u[0] = pkh(W1[arow * 17 + g4 * 8 + 0], W1[arow * 17 + g4 * 8 + 1]);
                wu.u[1] = pkh(W1[arow * 17 + g4 * 8 + 2], W1[arow * 17 + g4 * 8 + 3]);
                wu.u[2] = pkh(W1[arow * 17 + g4 * 8 + 4], W1[arow * 17 + g4 * 8 + 5]);
                wu.u[3] = pkh(W1[arow * 17 + g4 * 8 + 6], W1[arow * 17 + g4 * 8 + 7]);
            }
            f32x4 z0 = {0.f, 0.f, 0.f, 0.f};
            uc[m] = MFMA16(wu.f, yu.f, z0);
            uh[m] = uc[m];
            uf[m] = z0;
            hacc[m] = z0;
        }
    }

    float plsum = 0.f;
    int hidx[2];
#pragma unroll
    for (int m = 0; m < 2; ++m) {
        const int crow = w * 32 + m * 16 + g4 * 4;
        hidx[m] = ((crow >> 3) * 16 + col) * 8 + (crow & 7);
    }

    for (int e = 0; e <= 10; ++e) {
        const float t  = 0.1f * (float)e;
        const float wt = (e == 0 || e == 10) ? 0.05f : 0.1f;

        // ---- phase 0 (regs): uh' = 2uc-uh+dt*uf ; z1 = uh'+t*w1t+b1 ; h1 -> LDS
        //      (at e=0: uh=uc, uf=0 makes this exact-identical to z1=uc+b1) ----
        float s1v[2][4];
#pragma unroll
        for (int m = 0; m < 2; ++m) {
            float h1v[4];
#pragma unroll
            for (int r = 0; r < 4; ++r) {
                uh[m][r] = 2.f * uc[m][r] - uh[m][r] + 0.1f * uf[m][r];
                float zz = uh[m][r] + t * w1t[m][r] + b1r[m][r];
                float g  = 1.f / (1.f + __expf(-zz));
                float hh = zz * g;
                h1v[r] = hh;
                s1v[m][r] = g + hh * (1.f - g);
            }
            uint32_t* p = (uint32_t*)&H1[hidx[m]];
            p[0] = pkh(h1v[0], h1v[1]);
            p[1] = pkh(h1v[2], h1v[3]);
        }
        __syncthreads();   // A: H1 ready

        // ---- phase 1: z2 = W2 @ H1 + b2 ; h2, silu'2 -> LDS ----
        f16x8 Bf[4];
#pragma unroll
        for (int ks = 0; ks < 4; ++ks)
            Bf[ks] = *(const f16x8*)&H1[(g4 + ks * 4) * 128 + col * 8];
#pragma unroll
        for (int m = 0; m < 2; ++m) {
            f32x4 ca = {b2r[m][0], b2r[m][1], b2r[m][2], b2r[m][3]};
            f32x4 cb = {0.f, 0.f, 0.f, 0.f};
            ca = MFMA16(W2f[m][0], Bf[0], ca); cb = MFMA16(W2f[m][1], Bf[1], cb);
            ca = MFMA16(W2f[m][2], Bf[2], ca); cb = MFMA16(W2f[m][3], Bf[3], cb);
            float h2v[4], s2v[4];
#pragma unroll
            for (int r = 0; r < 4; ++r) {
                float zz = ca[r] + cb[r];
                float g  = 1.f / (1.f + __expf(-zz));
                float hh = zz * g;
                h2v[r] = hh;
                s2v[r] = g + hh * (1.f - g);
                hacc[m][r] += wt * hh;     // y-output accumulator (linear in h2)
            }
            if (e < 10) {
                uint32_t* p = (uint32_t*)&H2[hidx[m]];
                p[0] = pkh(h2v[0], h2v[1]);
                p[1] = pkh(h2v[2], h2v[3]);
            }
            uint32_t* p = (uint32_t*)&S2[hidx[m]];
            p[0] = pkh(s2v[0], s2v[1]);
            p[1] = pkh(s2v[2], s2v[3]);
        }
        __syncthreads();   // B: H2, S2 ready

        // ---- phase 2a: trace partial (G frags from LDS) ----
        f16x8 Sf[4];
#pragma unroll
        for (int ks = 0; ks < 4; ++ks)
            Sf[ks] = *(const f16x8*)&S2[(g4 + ks * 4) * 128 + col * 8];
        float p = 0.f;
#pragma unroll
        for (int m = 0; m < 2; ++m) {
            const int T = w * 2 + m;
            f16x8 ga0 = *(const f16x8*)&AG[AFOFF(T, 0, l)];
            f16x8 ga1 = *(const f16x8*)&AG[AFOFF(T, 1, l)];
            f16x8 ga2 = *(const f16x8*)&AG[AFOFF(T, 2, l)];
            f16x8 ga3 = *(const f16x8*)&AG[AFOFF(T, 3, l)];
            f32x4 c0 = {0.f, 0.f, 0.f, 0.f}, c1 = {0.f, 0.f, 0.f, 0.f};
            c0 = MFMA16(ga0, Sf[0], c0); c1 = MFMA16(ga1, Sf[1], c1);
            c0 = MFMA16(ga2, Sf[2], c0); c1 = MFMA16(ga3, Sf[3], c1);
#pragma unroll
            for (int r = 0; r < 4; ++r) p += s1v[m][r] * (c0[r] + c1[r]);
        }
        p += __shfl_xor(p, 16);
        p += __shfl_xor(p, 32);
        plsum += wt * p;

        // ---- phase 2b: uf_next = M @ H2 + W1y@b3 ; state update (skip at e=10) ----
        if (e < 10) {
            f16x8 Hf[4];
#pragma unroll
            for (int ks = 0; ks < 4; ++ks)
                Hf[ks] = *(const f16x8*)&H2[(g4 + ks * 4) * 128 + col * 8];
#pragma unroll
            for (int m = 0; m < 2; ++m) {
                const int T = w * 2 + m;
                f16x8 ma0 = *(const f16x8*)&AM[AFOFF(T, 0, l)];
                f16x8 ma1 = *(const f16x8*)&AM[AFOFF(T, 1, l)];
                f16x8 ma2 = *(const f16x8*)&AM[AFOFF(T, 2, l)];
                f16x8 ma3 = *(const f16x8*)&AM[AFOFF(T, 3, l)];
                f32x4 u0 = {ub3[m][0], ub3[m][1], ub3[m][2], ub3[m][3]};
                f32x4 u1 = {0.f, 0.f, 0.f, 0.f};
                u0 = MFMA16(ma0, Hf[0], u0); u1 = MFMA16(ma1, Hf[1], u1);
                u0 = MFMA16(ma2, Hf[2], u0); u1 = MFMA16(ma3, Hf[3], u1);
                if (e == 0) {
#pragma unroll
                    for (int r = 0; r < 4; ++r) uf[m][r] = u0[r] + u1[r];
                } else {
#pragma unroll
                    for (int r = 0; r < 4; ++r) {
                        float un = u0[r] + u1[r];
                        uc[m][r] += 0.05f * (uf[m][r] + un);
                        uf[m][r] = un;
                    }
                }
            }
        }
    }

    // ---- epilogue: y_out = y0 + W3 @ hacc + b3 ; l_out = wave-partial sum ----
#pragma unroll
    for (int m = 0; m < 2; ++m) {
        uint32_t* p = (uint32_t*)&H2[hidx[m]];   // safe: barrier A of e=10 since last read
        p[0] = pkh(hacc[m][0], hacc[m][1]);
        p[1] = pkh(hacc[m][2], hacc[m][3]);
    }
    if (l < 16) PS[w * 16 + l] = plsum;
    __syncthreads();
    if (w == 0) {
        f16x8 Hf[4], W3w[4];
#pragma unroll
        for (int ks = 0; ks < 4; ++ks) {
            Hf[ks] = *(const f16x8*)&H2[(g4 + ks * 4) * 128 + col * 8];
            const float4* pw = (const float4*)&W3[col * 128 + ks * 32 + g4 * 8];
            float4 a0 = pw[0], a1 = pw[1];
            f16x8 t = {(_Float16)a0.x, (_Float16)a0.y, (_Float16)a0.z, (_Float16)a0.w,
                       (_Float16)a1.x, (_Float16)a1.y, (_Float16)a1.z, (_Float16)a1.w};
            W3w[ks] = t;
        }
        f32x4 f0 = {b3[g4 * 4 + 0], b3[g4 * 4 + 1], b3[g4 * 4 + 2], b3[g4 * 4 + 3]};
        f32x4 f1 = {0.f, 0.f, 0.f, 0.f};
        f0 = MFMA16(W3w[0], Hf[0], f0); f1 = MFMA16(W3w[1], Hf[1], f1);
        f0 = MFMA16(W3w[2], Hf[2], f0); f1 = MFMA16(W3w[3], Hf[3], f1);
#pragma unroll
        for (int r = 0; r < 4; ++r)
            out[(sbase + col) * 16 + g4 * 4 + r] =
                y[(sbase + col) * 16 + g4 * 4 + r] + f0[r] + f1[r];
        if (l < 16) {
            float s = 0.f;
#pragma unroll
            for (int ww = 0; ww < 4; ++ww) s += PS[ww * 16 + l];
            out[4096 * 16 + sbase + l] = s;
        }
    }
}

extern "C" void kernel_launch(void* const* d_in, const int* in_sizes, int n_in,
                              void* d_out, int out_size, void* d_ws, size_t ws_size,
                              hipStream_t stream) {
    const float* y  = (const float*)d_in[0];
    const float* W1 = (const float*)d_in[1];
    const float* b1 = (const float*)d_in[2];
    const float* W2 = (const float*)d_in[3];
    const float* b2 = (const float*)d_in[4];
    const float* W3 = (const float*)d_in[5];
    const float* b3 = (const float*)d_in[6];
    float* out = (float*)d_out;

    cnf_main<<<256, 256, 0, stream>>>(y, W1, b1, W2, b2, W3, b3, out);
}

// Round 7
// 31.058 us; speedup vs baseline: 2.9389x; 1.5979x over previous
//
#include <hip/hip_runtime.h>
#include <stdint.h>

typedef _Float16 f16x8 __attribute__((ext_vector_type(8)));
typedef float f32x4 __attribute__((ext_vector_type(4)));

#define MFMA16(a, b, c) __builtin_amdgcn_mfma_f32_16x16x32_f16(a, b, c, 0, 0, 0)

static __device__ __forceinline__ uint32_t pkh(float a, float b) {
    union { _Float16 h[2]; uint32_t u; } v;
    v.h[0] = (_Float16)a; v.h[1] = (_Float16)b;
    return v.u;
}

// A-fragment LDS slot: tile T (rows T*16..T*16+15), k-block ks, lane l -> 8 f16
#define AFOFF(T, ks, l) (((((T) * 4 + (ks)) * 64) + (l)) * 8)

__launch_bounds__(512, 1)
__global__ void cnf_main(const float* __restrict__ y,
                         const float* __restrict__ W1, const float* __restrict__ b1,
                         const float* __restrict__ W2, const float* __restrict__ b2,
                         const float* __restrict__ W3, const float* __restrict__ b3,
                         float* __restrict__ out) {
    // G and M stationary A-fragments live in LDS (fragment-linear, conflict-free
    // b128 reads, zero cross-wave sharing) — LDS as spill-proof register file.
    __shared__ _Float16 AG[8 * 4 * 64 * 8];   // 32 KB
    __shared__ _Float16 AM[8 * 4 * 64 * 8];   // 32 KB
    // subtiled [kb=row>>3][col][row&7] f16: B-frag read = one ds_read_b128
    __shared__ _Float16 H1[16 * 128];
    __shared__ _Float16 H2[16 * 128];
    __shared__ _Float16 S2[16 * 128];
    __shared__ float PS[8 * 16];

    const int tid   = threadIdx.x;
    const int w     = tid >> 6;      // 8 waves, wave owns hidden rows [w*16, w*16+16)
    const int l     = tid & 63;
    const int col   = l & 15;        // sample column / A-frag tile row
    const int g4    = l >> 4;
    const int sbase = blockIdx.x * 16;
    const int arow  = w * 16 + col;          // A-frag hidden row
    const int crow  = w * 16 + g4 * 4;       // C-layout hidden row base

    // ---- W2 A-fragments in registers (16 VGPRs) ----
    f16x8 W2f[4];
#pragma unroll
    for (int ks = 0; ks < 4; ++ks) {
        const float4* pw = (const float4*)&W2[arow * 128 + ks * 32 + g4 * 8];
        float4 a0 = pw[0], a1 = pw[1];
        f16x8 t = {(_Float16)a0.x, (_Float16)a0.y, (_Float16)a0.z, (_Float16)a0.w,
                   (_Float16)a1.x, (_Float16)a1.y, (_Float16)a1.z, (_Float16)a1.w};
        W2f[ks] = t;
    }

    // ---- prologue: M = W1y@W3, G = M .* W2^T  -> LDS fragments (1 tile/wave) ----
    {
        float w1row[16];
#pragma unroll
        for (int mm = 0; mm < 16; ++mm) w1row[mm] = W1[arow * 17 + mm];
#pragma unroll
        for (int ks = 0; ks < 4; ++ks) {
            float macc[8];
#pragma unroll
            for (int j = 0; j < 8; ++j) macc[j] = 0.f;
#pragma unroll
            for (int mm = 0; mm < 16; ++mm) {
                const float4* pr = (const float4*)&W3[mm * 128 + ks * 32 + g4 * 8];
                float4 r0 = pr[0], r1 = pr[1];
                float wv = w1row[mm];
                macc[0] += wv * r0.x; macc[1] += wv * r0.y;
                macc[2] += wv * r0.z; macc[3] += wv * r0.w;
                macc[4] += wv * r1.x; macc[5] += wv * r1.y;
                macc[6] += wv * r1.z; macc[7] += wv * r1.w;
            }
            f16x8 mh, gh;
#pragma unroll
            for (int j = 0; j < 8; ++j) {
                mh[j] = (_Float16)macc[j];
                gh[j] = (_Float16)(macc[j] * W2[(ks * 32 + g4 * 8 + j) * 128 + arow]);
            }
            *(f16x8*)&AM[AFOFF(w, ks, l)] = mh;
            *(f16x8*)&AG[AFOFF(w, ks, l)] = gh;
        }
    }

    // ---- biases / projections ----
    float b1r[4], b2r[4], w1t[4], ub3[4];
#pragma unroll
    for (int r = 0; r < 4; ++r) {
        b1r[r] = b1[crow + r];
        b2r[r] = b2[crow + r];
        w1t[r] = W1[(crow + r) * 17 + 16];
        float acc = 0.f;
#pragma unroll
        for (int mm = 0; mm < 16; ++mm) acc += W1[(crow + r) * 17 + mm] * b3[mm];
        ub3[r] = acc;   // (W1y @ b3)[crow+r]
    }

    // ---- init: uc = W1y @ y0 (one MFMA); uh=uc, uf=0 ----
    f32x4 uc, uh, uf, hacc;
    {
        union { uint32_t u[4]; f16x8 f; } yu, wu;
#pragma unroll
        for (int q = 0; q < 4; ++q) { yu.u[q] = 0u; wu.u[q] = 0u; }
        if (g4 < 2) {
            const float4* py = (const float4*)&y[(sbase + col) * 16 + g4 * 8];
            float4 y0 = py[0], y1 = py[1];
            yu.u[0] = pkh(y0.x, y0.y); yu.u[1] = pkh(y0.z, y0.w);
            yu.u[2] = pkh(y1.x, y1.y); yu.u[3] = pkh(y1.z, y1.w);
            wu.u[0] = pkh(W1[arow * 17 + g4 * 8 + 0], W1[arow * 17 + g4 * 8 + 1]);
            wu.u[1] = pkh(W1[arow * 17 + g4 * 8 + 2], W1[arow * 17 + g4 * 8 + 3]);
            wu.u[2] = pkh(W1[arow * 17 + g4 * 8 + 4], W1[arow * 17 + g4 * 8 + 5]);
            wu.u[3] = pkh(W1[arow * 17 + g4 * 8 + 6], W1[arow * 17 + g4 * 8 + 7]);
        }
        f32x4 z0 = {0.f, 0.f, 0.f, 0.f};
        uc = MFMA16(wu.f, yu.f, z0);
        uh = uc;
        uf = z0;
        hacc = z0;
    }

    float plsum = 0.f;
    const int hidx = ((crow >> 3) * 16 + col) * 8 + (crow & 7);

    for (int e = 0; e <= 10; ++e) {
        const float t  = 0.1f * (float)e;
        const float wt = (e == 0 || e == 10) ? 0.05f : 0.1f;

        // ---- phase 0 (regs): uh' = 2uc-uh+dt*uf ; z1 = uh'+t*w1t+b1 ; h1 -> LDS
        //      (at e=0: uh=uc, uf=0 makes this exact-identical to z1=uc+b1) ----
        float s1v[4];
        {
            float h1v[4];
#pragma unroll
            for (int r = 0; r < 4; ++r) {
                uh[r] = 2.f * uc[r] - uh[r] + 0.1f * uf[r];
                float zz = uh[r] + t * w1t[r] + b1r[r];
                float g  = 1.f / (1.f + __expf(-zz));
                float hh = zz * g;
                h1v[r] = hh;
                s1v[r] = g + hh * (1.f - g);
            }
            uint32_t* p = (uint32_t*)&H1[hidx];
            p[0] = pkh(h1v[0], h1v[1]);
            p[1] = pkh(h1v[2], h1v[3]);
        }
        __syncthreads();   // A: H1 ready

        // ---- phase 1: z2 = W2 @ H1 + b2 ; h2, silu'2 -> LDS ----
        f16x8 Bf[4];
#pragma unroll
        for (int ks = 0; ks < 4; ++ks)
            Bf[ks] = *(const f16x8*)&H1[(g4 + ks * 4) * 128 + col * 8];
        {
            f32x4 ca = {b2r[0], b2r[1], b2r[2], b2r[3]};
            f32x4 cb = {0.f, 0.f, 0.f, 0.f};
            ca = MFMA16(W2f[0], Bf[0], ca); cb = MFMA16(W2f[1], Bf[1], cb);
            ca = MFMA16(W2f[2], Bf[2], ca); cb = MFMA16(W2f[3], Bf[3], cb);
            float h2v[4], s2v[4];
#pragma unroll
            for (int r = 0; r < 4; ++r) {
                float zz = ca[r] + cb[r];
                float g  = 1.f / (1.f + __expf(-zz));
                float hh = zz * g;
                h2v[r] = hh;
                s2v[r] = g + hh * (1.f - g);
                hacc[r] += wt * hh;     // y-output accumulator (linear in h2)
            }
            if (e < 10) {
                uint32_t* p = (uint32_t*)&H2[hidx];
                p[0] = pkh(h2v[0], h2v[1]);
                p[1] = pkh(h2v[2], h2v[3]);
            }
            uint32_t* p = (uint32_t*)&S2[hidx];
            p[0] = pkh(s2v[0], s2v[1]);
            p[1] = pkh(s2v[2], s2v[3]);
        }
        __syncthreads();   // B: H2, S2 ready

        // ---- phase 2a: trace partial (G frags from LDS) ----
        {
            f16x8 Sf[4];
#pragma unroll
            for (int ks = 0; ks < 4; ++ks)
                Sf[ks] = *(const f16x8*)&S2[(g4 + ks * 4) * 128 + col * 8];
            f16x8 ga0 = *(const f16x8*)&AG[AFOFF(w, 0, l)];
            f16x8 ga1 = *(const f16x8*)&AG[AFOFF(w, 1, l)];
            f16x8 ga2 = *(const f16x8*)&AG[AFOFF(w, 2, l)];
            f16x8 ga3 = *(const f16x8*)&AG[AFOFF(w, 3, l)];
            f32x4 c0 = {0.f, 0.f, 0.f, 0.f}, c1 = {0.f, 0.f, 0.f, 0.f};
            c0 = MFMA16(ga0, Sf[0], c0); c1 = MFMA16(ga1, Sf[1], c1);
            c0 = MFMA16(ga2, Sf[2], c0); c1 = MFMA16(ga3, Sf[3], c1);
            float p = 0.f;
#pragma unroll
            for (int r = 0; r < 4; ++r) p += s1v[r] * (c0[r] + c1[r]);
            p += __shfl_xor(p, 16);
            p += __shfl_xor(p, 32);
            plsum += wt * p;
        }

        // ---- phase 2b: uf_next = M @ H2 + W1y@b3 ; state update (skip at e=10) ----
        if (e < 10) {
            f16x8 Hf[4];
#pragma unroll
            for (int ks = 0; ks < 4; ++ks)
                Hf[ks] = *(const f16x8*)&H2[(g4 + ks * 4) * 128 + col * 8];
            f16x8 ma0 = *(const f16x8*)&AM[AFOFF(w, 0, l)];
            f16x8 ma1 = *(const f16x8*)&AM[AFOFF(w, 1, l)];
            f16x8 ma2 = *(const f16x8*)&AM[AFOFF(w, 2, l)];
            f16x8 ma3 = *(const f16x8*)&AM[AFOFF(w, 3, l)];
            f32x4 u0 = {ub3[0], ub3[1], ub3[2], ub3[3]};
            f32x4 u1 = {0.f, 0.f, 0.f, 0.f};
            u0 = MFMA16(ma0, Hf[0], u0); u1 = MFMA16(ma1, Hf[1], u1);
            u0 = MFMA16(ma2, Hf[2], u0); u1 = MFMA16(ma3, Hf[3], u1);
            if (e == 0) {
#pragma unroll
                for (int r = 0; r < 4; ++r) uf[r] = u0[r] + u1[r];
            } else {
#pragma unroll
                for (int r = 0; r < 4; ++r) {
                    float un = u0[r] + u1[r];
                    uc[r] += 0.05f * (uf[r] + un);
                    uf[r] = un;
                }
            }
        }
    }

    // ---- epilogue: y_out = y0 + W3 @ hacc + b3 ; l_out = wave-partial sum ----
    {
        uint32_t* p = (uint32_t*)&H2[hidx];   // safe: barrier B of e=10 since last H2 read
        p[0] = pkh(hacc[0], hacc[1]);
        p[1] = pkh(hacc[2], hacc[3]);
    }
    if (l < 16) PS[w * 16 + l] = plsum;
    __syncthreads();
    if (w == 0) {
        f16x8 Hf[4], W3w[4];
#pragma unroll
        for (int ks = 0; ks < 4; ++ks) {
            Hf[ks] = *(const f16x8*)&H2[(g4 + ks * 4) * 128 + col * 8];
            const float4* pw = (const float4*)&W3[col * 128 + ks * 32 + g4 * 8];
            float4 a0 = pw[0], a1 = pw[1];
            f16x8 t = {(_Float16)a0.x, (_Float16)a0.y, (_Float16)a0.z, (_Float16)a0.w,
                       (_Float16)a1.x, (_Float16)a1.y, (_Float16)a1.z, (_Float16)a1.w};
            W3w[ks] = t;
        }
        f32x4 f0 = {b3[g4 * 4 + 0], b3[g4 * 4 + 1], b3[g4 * 4 + 2], b3[g4 * 4 + 3]};
        f32x4 f1 = {0.f, 0.f, 0.f, 0.f};
        f0 = MFMA16(W3w[0], Hf[0], f0); f1 = MFMA16(W3w[1], Hf[1], f1);
        f0 = MFMA16(W3w[2], Hf[2], f0); f1 = MFMA16(W3w[3], Hf[3], f1);
#pragma unroll
        for (int r = 0; r < 4; ++r)
            out[(sbase + col) * 16 + g4 * 4 + r] =
                y[(sbase + col) * 16 + g4 * 4 + r] + f0[r] + f1[r];
        if (l < 16) {
            float s = 0.f;
#pragma unroll
            for (int ww = 0; ww < 8; ++ww) s += PS[ww * 16 + l];
            out[4096 * 16 + sbase + l] = s;
        }
    }
}

extern "C" void kernel_launch(void* const* d_in, const int* in_sizes, int n_in,
                              void* d_out, int out_size, void* d_ws, size_t ws_size,
                              hipStream_t stream) {
    const float* y  = (const float*)d_in[0];
    const float* W1 = (const float*)d_in[1];
    const float* b1 = (const float*)d_in[2];
    const float* W2 = (const float*)d_in[3];
    const float* b2 = (const float*)d_in[4];
    const float* W3 = (const float*)d_in[5];
    const float* b3 = (const float*)d_in[6];
    float* out = (float*)d_out;

    cnf_main<<<256, 512, 0, stream>>>(y, W1, b1, W2, b2, W3, b3, out);
}